// Round 6
// baseline (82.383 us; speedup 1.0000x reference)
//
#include <hip/hip_runtime.h>
#include <math.h>

// Problem constants
#define NCLS   100
#define BATCH_ 2048
#define OK     9        // POLICY_NUMS + 2
#define FHALF  64       // FEATURE_NUMS / 2

#define NLOGB  64       // logits blocks: 1024 thr = 16 waves, 2 rows/wave
#define NPOLB  16       // policy blocks: 64 pair-rows each, 4 streams on waves 0-3
#define NBLK   (NLOGB + NPOLB)

// Workspace layout (floats). Every slot below is written exactly once by its
// owning block (plain stores); the last-arriving block reduces.
#define LP_OFF 0                        // 64 x {ce, kl}
#define PS_OFF (LP_OFF + NLOGB * 2)     // 16 x 72 policy stats
#define PB_OFF (PS_OFF + NPOLB * 72)    // 16 x 320 policy buckets

// Module-scope arrival counter: init 0 at module load; last block resets it
// before combining so graph replays start clean. Not in d_ws (poison-safe).
__device__ int g_arrive = 0;

__device__ __forceinline__ float waveSum(float v) {
#pragma unroll
    for (int off = 32; off; off >>= 1) v += __shfl_xor(v, off, 64);
    return v;
}
__device__ __forceinline__ float waveMax(float v) {
#pragma unroll
    for (int off = 32; off; off >>= 1) v = fmaxf(v, __shfl_xor(v, off, 64));
    return v;
}
__device__ __forceinline__ double waveSumD(double v) {
#pragma unroll
    for (int off = 32; off; off >>= 1) v += __shfl_xor(v, off, 64);
    return v;
}

__global__ __launch_bounds__(1024) void fused_kernel(
        const float* __restrict__ slog, const float* __restrict__ tlog,
        const float* __restrict__ spol, const float* __restrict__ tpol,
        const float* __restrict__ W1,   const float* __restrict__ W2,
        const int*   __restrict__ tgt,
        const float* __restrict__ bias1, const float* __restrict__ bias2,
        float* __restrict__ ws, float* __restrict__ out)
{
    // policy-phase LDS
    __shared__ float4 w1s4[OK * 32];        // [OK][32] float4 = [OK][128] floats
    __shared__ float4 w2s4[OK * 32];
    __shared__ float  res[4 * OK * 64];     // [stream][k][lane] per-row dot results
    __shared__ float  bkt[320];
    __shared__ float  redL[64];             // 16 waves x {ce0, kl0, ce1, kl1}
    // combine-phase scratch (only the last block uses these)
    __shared__ float  statsC[72];
    __shared__ float  bktC[320];
    __shared__ int    lastFlag;

    const int tid  = threadIdx.x;
    const int wave = tid >> 6;
    const int lane = tid & 63;

    if (blockIdx.x < NLOGB) {
        // ---------- logits: CE + KL(T=4), TWO rows per wave (ILP), 32 rows/block ----
        const int r0 = blockIdx.x * 32 + wave * 2;         // 0..2046
        const float* xa = slog + r0 * NCLS;
        const float* ya = tlog + r0 * NCLS;
        const float* xb = xa + NCLS;
        const float* yb = ya + NCLS;
        const int lab0 = tgt[r0 * 8];                      // start indirect chains early
        const int lab1 = tgt[(r0 + 1) * 8];
        const bool has2 = lane < (NCLS - 64);
        float a1 = xa[lane], a2 = has2 ? xa[lane + 64] : -3.0e38f;
        float b1 = ya[lane], b2 = has2 ? ya[lane + 64] : -3.0e38f;
        float c1 = xb[lane], c2 = has2 ? xb[lane + 64] : -3.0e38f;
        float d1 = yb[lane], d2 = has2 ? yb[lane + 64] : -3.0e38f;
        float xl0 = xa[lab0], xl1 = xb[lab1];

        // independent shuffle chains for the two rows overlap
        float mxa = waveMax(fmaxf(a1, a2));
        float mxb = waveMax(fmaxf(b1, b2));
        float mxc = waveMax(fmaxf(c1, c2));
        float mxd = waveMax(fmaxf(d1, d2));

        float se1_0  = waveSum(expf(a1 - mxa) + (has2 ? expf(a2 - mxa) : 0.f));
        float se4s_0 = waveSum(expf((a1 - mxa) * 0.25f) + (has2 ? expf((a2 - mxa) * 0.25f) : 0.f));
        float e1_0 = expf((b1 - mxb) * 0.25f);
        float e2_0 = has2 ? expf((b2 - mxb) * 0.25f) : 0.f;
        float se4t_0 = waveSum(e1_0 + e2_0);
        float tnum_0 = waveSum(e1_0 * (b1 - a1) * 0.25f + (has2 ? e2_0 * (b2 - a2) * 0.25f : 0.f));

        float se1_1  = waveSum(expf(c1 - mxc) + (has2 ? expf(c2 - mxc) : 0.f));
        float se4s_1 = waveSum(expf((c1 - mxc) * 0.25f) + (has2 ? expf((c2 - mxc) * 0.25f) : 0.f));
        float e1_1 = expf((d1 - mxd) * 0.25f);
        float e2_1 = has2 ? expf((d2 - mxd) * 0.25f) : 0.f;
        float se4t_1 = waveSum(e1_1 + e2_1);
        float tnum_1 = waveSum(e1_1 * (d1 - c1) * 0.25f + (has2 ? e2_1 * (d2 - c2) * 0.25f : 0.f));

        if (lane == 0) {
            redL[wave * 4 + 0] = (mxa + logf(se1_0)) - xl0;
            float logZ4s_0 = mxa * 0.25f + logf(se4s_0);
            float logZ4t_0 = mxb * 0.25f + logf(se4t_0);
            redL[wave * 4 + 1] = tnum_0 / se4t_0 + logZ4s_0 - logZ4t_0;
            redL[wave * 4 + 2] = (mxc + logf(se1_1)) - xl1;
            float logZ4s_1 = mxc * 0.25f + logf(se4s_1);
            float logZ4t_1 = mxd * 0.25f + logf(se4t_1);
            redL[wave * 4 + 3] = tnum_1 / se4t_1 + logZ4s_1 - logZ4t_1;
        }
        __syncthreads();
        if (wave == 0) {
            // lane L holds redL[L]; xor {4,8,16,32} sums same (L&3) residue over
            // the 16 waves; final xor 2 folds row0+row1 -> lane0=ce, lane1=kl
            float v = redL[lane];
            v += __shfl_xor(v, 4, 64);
            v += __shfl_xor(v, 8, 64);
            v += __shfl_xor(v, 16, 64);
            v += __shfl_xor(v, 32, 64);
            v += __shfl_xor(v, 2, 64);
            if (lane < 2) ws[LP_OFF + blockIdx.x * 2 + lane] = v;
        }
    } else {
        // ---------- policy: 4 streams on 4 waves, lane = pair-row ----------
        const int pb = blockIdx.x - NLOGB;                 // 0..15

        // Early independent loads: issued BEFORE the weight-stage barrier so
        // their HBM/L2 latency overlaps the weight fetch instead of following it.
        int t1e = 0, t2e = 0;
        if (wave >= 8) {
            const int c0 = wave - 8;
            const int i  = pb * 64 + lane;
            t1e = tgt[(2 * i) * 8 + c0];
            t2e = tgt[(2 * i + 1) * 8 + c0];
        }
        const float* fbase = (wave & 2) ? tpol : spol;
        const float4* feat = (const float4*)(fbase + (2 * (pb * 64 + lane) + (wave & 1)) * FHALF);
        float4 fpre0, fpre1, fpre2, fpre3;
        if (wave < 4) { fpre0 = feat[0]; fpre1 = feat[1]; fpre2 = feat[2]; fpre3 = feat[3]; }

        if (tid < OK * 32) {
            w1s4[tid] = ((const float4*)W1)[tid];
            w2s4[tid] = ((const float4*)W2)[tid];
        }
        if (tid < 320) bkt[tid] = 0.f;
        __syncthreads();

        if (wave < 4) {
            // stream: 0 -> As = f1s . W2[:, :64]   1 -> Bs = f2s . W2[:, 64:]
            //         2 -> At = f1t . W1[:, :64]   3 -> Bt = f2t . W1[:, 64:]
            const float4* wb = (wave & 2) ? w1s4 : w2s4;
            const int colOff = (wave & 1) ? 16 : 0;

            float acc[OK];
#pragma unroll
            for (int k = 0; k < OK; ++k) acc[k] = 0.f;
            // first 4 f4-chunks from the prefetched registers
            float4 pre[4] = { fpre0, fpre1, fpre2, fpre3 };
#pragma unroll
            for (int j = 0; j < 4; ++j) {
                float4 fv = pre[j];
#pragma unroll
                for (int k = 0; k < OK; ++k) {
                    const float4 wv = wb[k * 32 + colOff + j];
                    acc[k] = fmaf(fv.x, wv.x, acc[k]);
                    acc[k] = fmaf(fv.y, wv.y, acc[k]);
                    acc[k] = fmaf(fv.z, wv.z, acc[k]);
                    acc[k] = fmaf(fv.w, wv.w, acc[k]);
                }
            }
#pragma unroll 4
            for (int f4 = 4; f4 < FHALF / 4; ++f4) {
                float4 fv = feat[f4];
#pragma unroll
                for (int k = 0; k < OK; ++k) {
                    // wave-uniform LDS address -> broadcast ds_read_b128
                    const float4 wv = wb[k * 32 + colOff + f4];
                    acc[k] = fmaf(fv.x, wv.x, acc[k]);
                    acc[k] = fmaf(fv.y, wv.y, acc[k]);
                    acc[k] = fmaf(fv.z, wv.z, acc[k]);
                    acc[k] = fmaf(fv.w, wv.w, acc[k]);
                }
            }
#pragma unroll
            for (int k = 0; k < OK; ++k)
                res[(wave * OK + k) * 64 + lane] = acc[k];  // stride-1: conflict-free
        }
        __syncthreads();

        if (wave < OK) {
            // wave k computes the 8 closed-form stats for output k over 64 rows
            const int k = wave;
            float A = res[(0 * OK + k) * 64 + lane];   // As
            float B = res[(1 * OK + k) * 64 + lane];   // Bs
            float C = res[(2 * OK + k) * 64 + lane];   // At
            float D = res[(3 * OK + k) * 64 + lane];   // Bt
            float du = B - D, dw = A - C;
            float v0 = waveSum(du),  v1 = waveSum(du * du);
            float v2 = waveSum(dw),  v3 = waveSum(dw * dw);
            float v4 = waveSum(B),   v5 = waveSum(B * B);
            float v6 = waveSum(A),   v7 = waveSum(A * A);
            if (lane == 0) {
                float* p = ws + PS_OFF + pb * 72 + k * 8;
                p[0] = v0; p[1] = v1; p[2] = v2; p[3] = v3;
                p[4] = v4; p[5] = v5; p[6] = v6; p[7] = v7;
            }
        }
        if (wave >= 8) {
            // buckets: wave 8..15 handles c0 = wave-8; 4 LDS atomics per lane
            const int c0 = wave - 8;
            atomicAdd(&bkt[0 * 80 + c0 * 10 + t1e], 1.0f);
            atomicAdd(&bkt[1 * 80 + c0 * 10 + t2e], 1.0f);
            atomicAdd(&bkt[2 * 80 + c0 * 10 + t1e], res[(0 * OK + c0 + 1) * 64 + lane]);
            atomicAdd(&bkt[3 * 80 + c0 * 10 + t2e], res[(1 * OK + c0 + 1) * 64 + lane]);
        }
        __syncthreads();
        if (tid < 320) ws[PB_OFF + pb * 320 + tid] = bkt[tid];
    }

    // ---------- last-block combine (replaces the second kernel launch) ----------
    __syncthreads();
    if (tid == 0) {
        __threadfence();                       // release: ws stores visible device-wide
        int old = atomicAdd(&g_arrive, 1);
        int last = (old == NBLK - 1);
        if (last) {
            g_arrive = 0;                      // re-arm for next launch / graph replay
            __threadfence();                   // acquire before ws reads
        }
        lastFlag = last;
    }
    __syncthreads();
    if (!lastFlag) return;

    // --- combine phase, executed by the single last-arriving block ---
    // LP (64x2) is reduced entirely inside wave 0, so ce/kl stay in registers.
    float ce = 0.f, kl = 0.f;
    if (tid < NLOGB) {
        ce = ws[LP_OFF + tid * 2];
        kl = ws[LP_OFF + tid * 2 + 1];
    }
    ce = waveSum(ce); kl = waveSum(kl);

    if (tid < 72) {
        float s = 0.f;
#pragma unroll
        for (int b = 0; b < NPOLB; ++b) s += ws[PS_OFF + b * 72 + tid];
        statsC[tid] = s;
    }
    if (tid < 320) {
        float s = 0.f;
#pragma unroll
        for (int b = 0; b < NPOLB; ++b) s += ws[PB_OFF + b * 320 + tid];
        bktC[tid] = s;
    }
    __syncthreads();                           // single combine barrier

    if (wave == 0) {
        const double N = 1024.0, M = 1048576.0;

        // per-output stats on lanes 0..8 (registers, no LDS round trip)
        double klv = 0.0, SumL = 0.0, SumL2 = 0.0;
        if (lane < OK) {
            const int k = lane;
            const float* p = &statsC[k * 8];
            double D1u = p[0], D2u = p[1], D1w = p[2], D2w = p[3];
            double U1 = p[4], U2 = p[5], Wa1 = p[6], Wa2 = p[7];
            double cd = (double)bias2[k] - (double)bias1[k];
            double b  = (double)bias2[k];
            double S = N * D2u + N * (D2w + 2.0 * cd * D1w + N * cd * cd)
                     + 2.0 * D1u * (D1w + N * cd);
            klv = (k == 0) ? S / M
                : (k == 1) ? 0.5 * S / M
                : 0.001 * S / (7.0 * M);
            SumL  = N * U1 + N * Wa1 + M * b;
            SumL2 = N * U2 + N * (Wa2 + 2.0 * b * Wa1 + N * b * b)
                  + 2.0 * U1 * (Wa1 + N * b);
        }
        // lane c0 needs SumL/SumL2 of k=c0+1: pull from lane+1
        double SumLn  = __shfl(SumL,  (lane + 1) & 63, 64);
        double SumL2n = __shfl(SumL2, (lane + 1) & 63, 64);

        // bucket dot-products on lanes 0..7
        double cev = 0.0;
        if (lane < 8) {
            const int c0 = lane;
            const float* cnt1 = &bktC[0];
            const float* cnt2 = &bktC[80];
            const float* sA   = &bktC[160];
            const float* sB   = &bktC[240];
            double ms = 0.0, pc = 0.0;
            for (int v = 0; v < 10; ++v) {
                double c1 = (double)cnt1[c0 * 10 + v], c2 = (double)cnt2[c0 * 10 + v];
                ms += c1 * (double)sB[c0 * 10 + v] + c2 * (double)sA[c0 * 10 + v];
                pc += c1 * c2;
            }
            ms += (double)bias2[c0 + 1] * pc;
            if (c0 == 0) {
                cev = -0.5 * ms / M;                      // ce_C
            } else {
                double sg = 2.0 * ms - SumLn;             // SumLs[c0+1]
                cev = (SumL2n - 2.0 * sg + M) * (0.001 / (7.0 * M));
            }
        }

        double kl_pol = waveSumD(klv);                    // lanes >=9 contribute 0
        double ce_pol = waveSumD(cev);                    // lanes >=8 contribute 0

        if (lane == 0) {
            double ce_main = (double)ce / (double)BATCH_;
            double kl_main = (double)kl * 16.0 / (double)(BATCH_ * NCLS);
            double ce_I = -((double)statsC[4] + (double)statsC[6]
                            + N * (double)bias2[0]) / M;
            out[0] = (float)(ce_main + kl_main + kl_pol + ce_I + ce_pol);
        }
    }
}

extern "C" void kernel_launch(void* const* d_in, const int* in_sizes, int n_in,
                              void* d_out, int out_size, void* d_ws, size_t ws_size,
                              hipStream_t stream) {
    const float* slog = (const float*)d_in[0];
    const float* tlog = (const float*)d_in[1];
    const float* spol = (const float*)d_in[2];
    const float* tpol = (const float*)d_in[3];
    const float* W1   = (const float*)d_in[4];
    const float* b1   = (const float*)d_in[5];
    const float* W2   = (const float*)d_in[6];
    const float* b2   = (const float*)d_in[7];
    const int*   tgt  = (const int*)d_in[8];
    float* ws = (float*)d_ws;

    fused_kernel<<<NBLK, 1024, 0, stream>>>(slog, tlog, spol, tpol, W1, W2, tgt,
                                            b1, b2, ws, (float*)d_out);
}